// Round 3
// baseline (106.642 us; speedup 1.0000x reference)
//
#include <hip/hip_runtime.h>
#include <math.h>

#define NIN 128
#define NOUT 128
#define BB 4              // batch rows per block
#define NTH 256

// K-loop over chunks of 16 elements (4 float4 each of w, b, x-row0, x-row1).
// All loads issue before the FMA burst -> deep vmcnt pipelining.
template <bool STATS>
__device__ __forceinline__ void dot_loop(
    const float4* __restrict__ w4, const float4* __restrict__ b4,
    const float4* __restrict__ x40, const float4* __restrict__ x41,
    float& acb0, float& acw0, float& acb1, float& acw1,
    float& uu, float& bw, float& ww)
{
    #pragma unroll
    for (int ch = 0; ch < NIN / 16; ++ch) {
        float4 wv[4], bv[4], xv0[4], xv1[4];
        #pragma unroll
        for (int j = 0; j < 4; ++j) {
            wv[j]  = w4[ch * 4 + j];
            bv[j]  = b4[ch * 4 + j];
            xv0[j] = x40[ch * 4 + j];   // same address across lane -> broadcast
            xv1[j] = x41[ch * 4 + j];
        }
        #pragma unroll
        for (int j = 0; j < 4; ++j) {
            if (STATS) {
                uu = fmaf(bv[j].x, bv[j].x, uu); uu = fmaf(bv[j].y, bv[j].y, uu);
                uu = fmaf(bv[j].z, bv[j].z, uu); uu = fmaf(bv[j].w, bv[j].w, uu);
                bw = fmaf(bv[j].x, wv[j].x, bw); bw = fmaf(bv[j].y, wv[j].y, bw);
                bw = fmaf(bv[j].z, wv[j].z, bw); bw = fmaf(bv[j].w, wv[j].w, bw);
                ww = fmaf(wv[j].x, wv[j].x, ww); ww = fmaf(wv[j].y, wv[j].y, ww);
                ww = fmaf(wv[j].z, wv[j].z, ww); ww = fmaf(wv[j].w, wv[j].w, ww);
            }
            acb0 = fmaf(xv0[j].x, bv[j].x, acb0); acb0 = fmaf(xv0[j].y, bv[j].y, acb0);
            acb0 = fmaf(xv0[j].z, bv[j].z, acb0); acb0 = fmaf(xv0[j].w, bv[j].w, acb0);
            acw0 = fmaf(xv0[j].x, wv[j].x, acw0); acw0 = fmaf(xv0[j].y, wv[j].y, acw0);
            acw0 = fmaf(xv0[j].z, wv[j].z, acw0); acw0 = fmaf(xv0[j].w, wv[j].w, acw0);
            acb1 = fmaf(xv1[j].x, bv[j].x, acb1); acb1 = fmaf(xv1[j].y, bv[j].y, acb1);
            acb1 = fmaf(xv1[j].z, bv[j].z, acb1); acb1 = fmaf(xv1[j].w, bv[j].w, acb1);
            acw1 = fmaf(xv1[j].x, wv[j].x, acw1); acw1 = fmaf(xv1[j].y, wv[j].y, acw1);
            acw1 = fmaf(xv1[j].z, wv[j].z, acw1); acw1 = fmaf(xv1[j].w, wv[j].w, acw1);
        }
    }
}

__global__ __launch_bounds__(NTH) void hyper_kernel(
    const float* __restrict__ x,
    const float* __restrict__ weight,
    const float* __restrict__ bias,
    float* __restrict__ out)
{
    __shared__ float svv[BB];
    __shared__ float s_uu[NOUT];
    __shared__ float s_bw[NOUT];
    __shared__ float s_ww[NOUT];

    const int tid = threadIdx.x;
    const int b0 = blockIdx.x * BB;
    const int o = tid & (NOUT - 1);
    const int rh = tid >> 7;                 // 0 or 1 (wave-uniform)

    // ---- vv[r] = ||x[b0+r]||^2 : threads 0..127, 32 lanes per row
    if (tid < 32 * BB) {
        const int r = tid >> 5, seg = tid & 31;
        const float4 v = *(const float4*)(x + (size_t)(b0 + r) * NIN + seg * 4);
        float s = fmaf(v.x, v.x, fmaf(v.y, v.y, fmaf(v.z, v.z, v.w * v.w)));
        s += __shfl_xor(s, 1);
        s += __shfl_xor(s, 2);
        s += __shfl_xor(s, 4);
        s += __shfl_xor(s, 8);
        s += __shfl_xor(s, 16);
        if (seg == 0) svv[r] = s;
    }

    const int row0 = b0 + rh * 2;
    const float4* x40 = (const float4*)(x + (size_t)row0 * NIN);
    const float4* x41 = x40 + NIN / 4;
    const float4* w4 = (const float4*)(weight + (size_t)o * NIN);
    const float4* b4 = (const float4*)(bias + (size_t)o * NIN);

    float acb0 = 0.f, acw0 = 0.f, acb1 = 0.f, acw1 = 0.f;
    float uu = 0.f, bw = 0.f, ww = 0.f;

    if (rh == 0) {
        dot_loop<true>(w4, b4, x40, x41, acb0, acw0, acb1, acw1, uu, bw, ww);
        s_uu[o] = uu; s_bw[o] = bw; s_ww[o] = ww;
    } else {
        dot_loop<false>(w4, b4, x40, x41, acb0, acw0, acb1, acw1, uu, bw, ww);
    }
    __syncthreads();
    uu = s_uu[o]; bw = s_bw[o]; ww = s_ww[o];
    const float vv0 = svv[rh * 2 + 0];
    const float vv1 = svv[rh * 2 + 1];

    // ---- epilogue (fp32, numerically stable softplus)
    const float EPS = 1.1920928955078125e-7f;
    const float CLAMPV = 16.635532333438687f;
    const float INV_SMOOTH = 1.f / 50.f;
    const float SMOOTHF = 50.f;
    const float MAXNORM = 1.f - 1e-5f;

    const float beta = 1.f - uu;
    const float beta_c = fmaxf(beta, EPS);
    const float a_norm = fmaxf(beta_c * sqrtf(ww), 1e-15f);
    const float ba = beta_c * bw;
    const float outcoef = (2.f / beta_c) * a_norm;
    const float inv_anorm = 1.f / a_norm;

    float accb[2] = {acb0, acb1};
    float accw[2] = {acw0, acw1};
    float vvs[2] = {vv0, vv1};

    #pragma unroll
    for (int r = 0; r < 2; ++r) {
        const float vv = vvs[r];
        const float uv = -accb[r];
        const float dax = beta_c * accw[r];
        const float alpha = 1.f + 2.f * uv + vv;
        const float den = fmaxf(1.f + 2.f * uv + uu * vv, EPS);
        const float inv_den = 1.f / den;
        float suba = (beta * dax - alpha * ba) * inv_den;
        float ss = (alpha * alpha * uu + 2.f * alpha * beta * uv + beta * beta * vv)
                   * (inv_den * inv_den);
        const float nrm = fmaxf(sqrtf(fmaxf(ss, 0.f)), 1e-15f);
        if (nrm > MAXNORM) {
            const float sc = MAXNORM / nrm;
            suba *= sc;
            ss *= sc * sc;
        }
        const float lam_sub = 2.f / fmaxf(1.f - ss, EPS);
        const float arg = lam_sub * suba * inv_anorm;
        const float t1 = SMOOTHF * (arg + CLAMPV);
        const float t2 = SMOOTHF * (arg - CLAMPV);
        const float sp1 = fmaxf(t1, 0.f) + log1pf(expf(-fabsf(t1)));
        const float sp2 = fmaxf(t2, 0.f) + log1pf(expf(-fabsf(t2)));
        const float scl = -CLAMPV + (sp1 - sp2) * INV_SMOOTH;
        const float sd = asinhf(scl);
        out[(size_t)(row0 + r) * NOUT + o] = outcoef * sd;
    }
}

extern "C" void kernel_launch(void* const* d_in, const int* in_sizes, int n_in,
                              void* d_out, int out_size, void* d_ws, size_t ws_size,
                              hipStream_t stream) {
    const float* x = (const float*)d_in[0];
    const float* w = (const float*)d_in[1];
    const float* b = (const float*)d_in[2];
    float* out = (float*)d_out;
    const int B = in_sizes[0] / NIN;       // 4096
    dim3 grid(B / BB), block(NTH);
    hipLaunchKernelGGL(hyper_kernel, grid, block, 0, stream, x, w, b, out);
}

// Round 4
// 77.981 us; speedup vs baseline: 1.3675x; 1.3675x over previous
//
#include <hip/hip_runtime.h>
#include <math.h>

#define NIN 128
#define NOUT 128
#define ROWS_PER_BLOCK 32
#define COLS_PER_BLOCK 16     // 4 waves x 4 cols
#define NTH 256

// DPP rotate within 16-lane row: lane i gets lane (i+N)%16's value. Pure VALU.
template <int N>
__device__ __forceinline__ float row_ror(float v) {
    return __int_as_float(__builtin_amdgcn_update_dpp(
        0, __float_as_int(v), 0x120 + N, 0xF, 0xF, true));
}

// Sum across the 16-lane group; result (up to rounding order) in all 16 lanes.
__device__ __forceinline__ float red16(float v) {
    v += row_ror<1>(v);
    v += row_ror<2>(v);
    v += row_ror<4>(v);
    v += row_ror<8>(v);
    return v;
}

__device__ __forceinline__ float dot8(float4 a0, float4 a1, float4 b0, float4 b1) {
    float s = a0.x * b0.x;
    s = fmaf(a0.y, b0.y, s);
    s = fmaf(a0.z, b0.z, s);
    s = fmaf(a0.w, b0.w, s);
    s = fmaf(a1.x, b1.x, s);
    s = fmaf(a1.y, b1.y, s);
    s = fmaf(a1.z, b1.z, s);
    s = fmaf(a1.w, b1.w, s);
    return s;
}

__device__ __forceinline__ float epilogue(
    float uv, float xw, float vv,
    float uu, float beta, float beta_c, float ba,
    float inv_anorm, float outcoef)
{
    const float EPS = 1.1920928955078125e-7f;
    const float CLAMPV = 16.635532333438687f;
    const float INV_SMOOTH = 1.f / 50.f;
    const float SMOOTHF = 50.f;
    const float MAXNORM = 1.f - 1e-5f;

    const float dax = beta_c * xw;
    const float alpha = 1.f + 2.f * uv + vv;
    const float den = fmaxf(1.f + 2.f * uv + uu * vv, EPS);
    const float inv_den = 1.f / den;
    float suba = (beta * dax - alpha * ba) * inv_den;
    float ss = (alpha * alpha * uu + 2.f * alpha * beta * uv + beta * beta * vv)
               * (inv_den * inv_den);
    const float nrm = fmaxf(sqrtf(fmaxf(ss, 0.f)), 1e-15f);
    if (nrm > MAXNORM) {
        const float sc = MAXNORM / nrm;
        suba *= sc;
        ss *= sc * sc;
    }
    const float lam_sub = 2.f / fmaxf(1.f - ss, EPS);
    const float arg = lam_sub * suba * inv_anorm;
    const float t1 = SMOOTHF * (arg + CLAMPV);
    const float t2 = SMOOTHF * (arg - CLAMPV);
    const float sp1 = fmaxf(t1, 0.f) + log1pf(expf(-fabsf(t1)));
    const float sp2 = fmaxf(t2, 0.f) + log1pf(expf(-fabsf(t2)));
    const float scl = -CLAMPV + (sp1 - sp2) * INV_SMOOTH;
    return outcoef * asinhf(scl);
}

__global__ __launch_bounds__(NTH) void hyper_kernel(
    const float* __restrict__ x,
    const float* __restrict__ weight,
    const float* __restrict__ bias,
    float* __restrict__ out)
{
    const int tid = threadIdx.x;
    const int wave = tid >> 6;           // 0..3
    const int lane = tid & 63;
    const int g = lane >> 4;             // column group within wave, 0..3
    const int t = lane & 15;             // k-slice within group
    const int blk_col = blockIdx.x & 7;  // 8 column blocks
    const int blk_row = blockIdx.x >> 3; // row blocks
    const int o = blk_col * COLS_PER_BLOCK + wave * 4 + g;
    const int rb = blk_row * ROWS_PER_BLOCK;

    // Column fragments live in registers for the entire kernel (coalesced load).
    const float4* wp = (const float4*)(weight + (size_t)o * NIN + t * 8);
    const float4* bp = (const float4*)(bias + (size_t)o * NIN + t * 8);
    const float4 wr0 = wp[0], wr1 = wp[1];
    const float4 br0 = bp[0], br1 = bp[1];

    // Per-column stats, one reduction each.
    const float uu = red16(dot8(br0, br1, br0, br1));
    const float bw = red16(dot8(br0, br1, wr0, wr1));
    const float ww = red16(dot8(wr0, wr1, wr0, wr1));

    const float EPS = 1.1920928955078125e-7f;
    const float beta = 1.f - uu;
    const float beta_c = fmaxf(beta, EPS);
    const float a_norm = fmaxf(beta_c * sqrtf(ww), 1e-15f);
    const float ba = beta_c * bw;
    const float outcoef = (2.f / beta_c) * a_norm;
    const float inv_anorm = 1.f / a_norm;

    const float* xbase = x + (size_t)rb * NIN + t * 8;

    #pragma unroll
    for (int c = 0; c < ROWS_PER_BLOCK / 16; ++c) {
        float uvK = 0.f, xwK = 0.f, vvK = 0.f;
        #pragma unroll 4
        for (int r = 0; r < 16; ++r) {
            const float4* xp = (const float4*)(xbase + (size_t)(c * 16 + r) * NIN);
            const float4 xv0 = xp[0];
            const float4 xv1 = xp[1];
            float pb = dot8(xv0, xv1, br0, br1);
            float pw = dot8(xv0, xv1, wr0, wr1);
            float pv = dot8(xv0, xv1, xv0, xv1);
            pb = red16(pb);
            pw = red16(pw);
            pv = red16(pv);
            if (t == r) { uvK = -pb; xwK = pw; vvK = pv; }
        }
        const float val = epilogue(uvK, xwK, vvK, uu, beta, beta_c, ba,
                                   inv_anorm, outcoef);
        out[(size_t)(rb + c * 16 + t) * NOUT + o] = val;
    }
}

extern "C" void kernel_launch(void* const* d_in, const int* in_sizes, int n_in,
                              void* d_out, int out_size, void* d_ws, size_t ws_size,
                              hipStream_t stream) {
    const float* x = (const float*)d_in[0];
    const float* w = (const float*)d_in[1];
    const float* b = (const float*)d_in[2];
    float* out = (float*)d_out;
    const int B = in_sizes[0] / NIN;                  // 4096
    dim3 grid((NOUT / COLS_PER_BLOCK) * (B / ROWS_PER_BLOCK)), block(NTH);
    hipLaunchKernelGGL(hyper_kernel, grid, block, 0, stream, x, w, b, out);
}

// Round 5
// 73.108 us; speedup vs baseline: 1.4587x; 1.0666x over previous
//
#include <hip/hip_runtime.h>
#include <math.h>

typedef __attribute__((ext_vector_type(8))) short short8;
typedef __attribute__((ext_vector_type(4))) float floatx4;

#define NIN 128
#define NOUT 128

__device__ __forceinline__ unsigned short f2bf(float f) {
    unsigned u = __float_as_uint(f);
    unsigned r = (u + 0x7fffu + ((u >> 16) & 1u)) >> 16;   // RNE
    return (unsigned short)r;
}
__device__ __forceinline__ float bf2f(unsigned short h) {
    return __uint_as_float(((unsigned)h) << 16);
}

// ---------------- prep: fp32 -> bf16 hi/lo, row norms, column constants -----
__global__ __launch_bounds__(256) void hyper_prep(
    const float* __restrict__ x, const float* __restrict__ w,
    const float* __restrict__ bia,
    unsigned short* __restrict__ xhi, unsigned short* __restrict__ xlo,
    unsigned short* __restrict__ whi, unsigned short* __restrict__ wlo,
    unsigned short* __restrict__ bhi, unsigned short* __restrict__ blo,
    float* __restrict__ vvp, float* __restrict__ colc)
{
    const int wave = threadIdx.x >> 6;
    const int lane = threadIdx.x & 63;
    if (blockIdx.x < 1024) {
        // one wave per x-row: convert + vv
        const int row = blockIdx.x * 4 + wave;
        const float2 v = *(const float2*)(x + (size_t)row * NIN + lane * 2);
        const unsigned short h0 = f2bf(v.x), h1 = f2bf(v.y);
        ushort2 hh; hh.x = h0; hh.y = h1;
        ushort2 ll; ll.x = f2bf(v.x - bf2f(h0)); ll.y = f2bf(v.y - bf2f(h1));
        *(ushort2*)(xhi + (size_t)row * NIN + lane * 2) = hh;
        *(ushort2*)(xlo + (size_t)row * NIN + lane * 2) = ll;
        float s = fmaf(v.x, v.x, v.y * v.y);
        #pragma unroll
        for (int m = 1; m < 64; m <<= 1) s += __shfl_xor(s, m);
        if (lane == 0) vvp[row] = s;
    } else {
        // one wave per column: convert w/b + full-precision column stats
        const int col = (blockIdx.x - 1024) * 4 + wave;
        const size_t base = (size_t)col * NIN;
        const float w0 = w[base + lane], w1 = w[base + 64 + lane];
        const float b0 = bia[base + lane], b1 = bia[base + 64 + lane];
        const unsigned short wh0 = f2bf(w0), wh1 = f2bf(w1);
        const unsigned short bh0 = f2bf(b0), bh1 = f2bf(b1);
        whi[base + lane] = wh0;            whi[base + 64 + lane] = wh1;
        wlo[base + lane] = f2bf(w0 - bf2f(wh0)); wlo[base + 64 + lane] = f2bf(w1 - bf2f(wh1));
        bhi[base + lane] = bh0;            bhi[base + 64 + lane] = bh1;
        blo[base + lane] = f2bf(b0 - bf2f(bh0)); blo[base + 64 + lane] = f2bf(b1 - bf2f(bh1));
        float uu = fmaf(b0, b0, b1 * b1);
        float bw = fmaf(b0, w0, b1 * w1);
        float ww = fmaf(w0, w0, w1 * w1);
        #pragma unroll
        for (int m = 1; m < 64; m <<= 1) {
            uu += __shfl_xor(uu, m);
            bw += __shfl_xor(bw, m);
            ww += __shfl_xor(ww, m);
        }
        if (lane == 0) {
            const float EPS = 1.1920928955078125e-7f;
            const float beta = 1.f - uu;
            const float beta_c = fmaxf(beta, EPS);
            const float a_norm = fmaxf(beta_c * sqrtf(ww), 1e-15f);
            float4 c;
            c.x = uu;
            c.y = beta_c * bw;              // bias . a
            c.z = 1.f / a_norm;
            c.w = (2.f / beta_c) * a_norm;  // lam_b * a_norm
            *(float4*)(colc + (size_t)col * 4) = c;
        }
    }
}

// ---------------- main: MFMA GEMMs + epilogue --------------------------------
__global__ __launch_bounds__(256) void hyper_main(
    const unsigned short* __restrict__ xhi, const unsigned short* __restrict__ xlo,
    const unsigned short* __restrict__ whi, const unsigned short* __restrict__ wlo,
    const unsigned short* __restrict__ bhi, const unsigned short* __restrict__ blo,
    const float* __restrict__ vvp, const float* __restrict__ colc,
    float* __restrict__ out)
{
    const int wave = threadIdx.x >> 6;
    const int lane = threadIdx.x & 63;
    const int q = lane >> 4, i = lane & 15;
    const int m0 = (blockIdx.x >> 1) * 16;                 // batch-row tile
    const int n0 = ((blockIdx.x & 1) * 4 + wave) * 16;     // out-col tile

    const size_t abase = (size_t)(m0 + i) * NIN + q * 8;   // A: m=lane&15, k=q*8+j
    const size_t bbase = (size_t)(n0 + i) * NIN + q * 8;   // B: n=lane&15, k=q*8+j

    short8 ah[4], al[4], wh[4], wl[4], bh[4], bl[4];
    #pragma unroll
    for (int kc = 0; kc < 4; ++kc) {
        ah[kc] = *(const short8*)(xhi + abase + kc * 32);
        al[kc] = *(const short8*)(xlo + abase + kc * 32);
        wh[kc] = *(const short8*)(whi + bbase + kc * 32);
        wl[kc] = *(const short8*)(wlo + bbase + kc * 32);
        bh[kc] = *(const short8*)(bhi + bbase + kc * 32);
        bl[kc] = *(const short8*)(blo + bbase + kc * 32);
    }

    floatx4 accW1 = {0.f, 0.f, 0.f, 0.f}, accW2 = {0.f, 0.f, 0.f, 0.f};
    floatx4 accB1 = {0.f, 0.f, 0.f, 0.f}, accB2 = {0.f, 0.f, 0.f, 0.f};
    #pragma unroll
    for (int kc = 0; kc < 4; ++kc) {
        accW1 = __builtin_amdgcn_mfma_f32_16x16x32_bf16(ah[kc], wh[kc], accW1, 0, 0, 0);
        accB1 = __builtin_amdgcn_mfma_f32_16x16x32_bf16(ah[kc], bh[kc], accB1, 0, 0, 0);
        accW2 = __builtin_amdgcn_mfma_f32_16x16x32_bf16(ah[kc], wl[kc], accW2, 0, 0, 0);
        accB2 = __builtin_amdgcn_mfma_f32_16x16x32_bf16(ah[kc], bl[kc], accB2, 0, 0, 0);
        accW2 = __builtin_amdgcn_mfma_f32_16x16x32_bf16(al[kc], wh[kc], accW2, 0, 0, 0);
        accB2 = __builtin_amdgcn_mfma_f32_16x16x32_bf16(al[kc], bh[kc], accB2, 0, 0, 0);
    }

    // per-column constants (full fp32 precision, from prep)
    const float4 cc = *(const float4*)(colc + (size_t)(n0 + i) * 4);
    const float uu = cc.x, ba = cc.y, inv_anorm = cc.z, outcoef = cc.w;

    const float EPS = 1.1920928955078125e-7f;
    const float CLAMPV = 16.635532333438687f;
    const float INV_SMOOTH = 1.f / 50.f;
    const float SMOOTHF = 50.f;
    const float MAXNORM = 1.f - 1e-5f;
    const float beta = 1.f - uu;
    const float beta_c = fmaxf(beta, EPS);

    #pragma unroll
    for (int r = 0; r < 4; ++r) {
        const int row = m0 + q * 4 + r;              // C/D: row = quad*4 + reg
        const float vv = vvp[row];
        const float uv = -(accB1[r] + accB2[r]);
        const float xw = accW1[r] + accW2[r];
        const float dax = beta_c * xw;
        const float alpha = 1.f + 2.f * uv + vv;
        const float den = fmaxf(1.f + 2.f * uv + uu * vv, EPS);
        const float inv_den = 1.f / den;
        float suba = (beta * dax - alpha * ba) * inv_den;
        float ss = (alpha * alpha * uu + 2.f * alpha * beta * uv + beta * beta * vv)
                   * (inv_den * inv_den);
        const float nrm = fmaxf(sqrtf(fmaxf(ss, 0.f)), 1e-15f);
        if (nrm > MAXNORM) {
            const float sc = MAXNORM / nrm;
            suba *= sc;
            ss *= sc * sc;
        }
        const float lam_sub = 2.f / fmaxf(1.f - ss, EPS);
        const float arg = lam_sub * suba * inv_anorm;
        const float t1 = SMOOTHF * (arg + CLAMPV);
        const float t2 = SMOOTHF * (arg - CLAMPV);
        const float sp1 = fmaxf(t1, 0.f) + log1pf(expf(-fabsf(t1)));
        const float sp2 = fmaxf(t2, 0.f) + log1pf(expf(-fabsf(t2)));
        const float scl = -CLAMPV + (sp1 - sp2) * INV_SMOOTH;
        out[(size_t)row * NOUT + n0 + i] = outcoef * asinhf(scl);
    }
}

extern "C" void kernel_launch(void* const* d_in, const int* in_sizes, int n_in,
                              void* d_out, int out_size, void* d_ws, size_t ws_size,
                              hipStream_t stream) {
    const float* x = (const float*)d_in[0];
    const float* w = (const float*)d_in[1];
    const float* b = (const float*)d_in[2];
    float* out = (float*)d_out;

    unsigned short* xhi = (unsigned short*)d_ws;           // 4096*128
    unsigned short* xlo = xhi + 524288;
    unsigned short* whi = xlo + 524288;                    // 128*128
    unsigned short* wlo = whi + 16384;
    unsigned short* bhi = wlo + 16384;
    unsigned short* blo = bhi + 16384;
    float* vvp = (float*)(blo + 16384);                    // 4096
    float* colc = vvp + 4096;                              // 128*4

    hipLaunchKernelGGL(hyper_prep, dim3(1056), dim3(256), 0, stream,
                       x, w, b, xhi, xlo, whi, wlo, bhi, blo, vvp, colc);
    hipLaunchKernelGGL(hyper_main, dim3(512), dim3(256), 0, stream,
                       xhi, xlo, whi, wlo, bhi, blo, vvp, colc, out);
}

// Round 6
// 64.734 us; speedup vs baseline: 1.6474x; 1.1294x over previous
//
#include <hip/hip_runtime.h>
#include <math.h>

typedef __attribute__((ext_vector_type(8))) short short8;
typedef __attribute__((ext_vector_type(4))) float floatx4;

#define NIN 128
#define NOUT 128
#define NTH 256

union FragU { unsigned u[4]; short8 s; };

// Split 8 fp32 (two float4) into bf16 hi (trunc) + bf16 lo (trunc residual).
// Packing via v_perm_b32: dst = {u1[31:16], u0[31:16]}.
__device__ __forceinline__ void cvt_frag(float4 a, float4 b, short8& hi, short8& lo) {
    const unsigned SEL = 0x07060302u;
    unsigned ua0 = __float_as_uint(a.x), ua1 = __float_as_uint(a.y);
    unsigned ua2 = __float_as_uint(a.z), ua3 = __float_as_uint(a.w);
    unsigned ub0 = __float_as_uint(b.x), ub1 = __float_as_uint(b.y);
    unsigned ub2 = __float_as_uint(b.z), ub3 = __float_as_uint(b.w);
    FragU h, l;
    h.u[0] = __builtin_amdgcn_perm(ua1, ua0, SEL);
    h.u[1] = __builtin_amdgcn_perm(ua3, ua2, SEL);
    h.u[2] = __builtin_amdgcn_perm(ub1, ub0, SEL);
    h.u[3] = __builtin_amdgcn_perm(ub3, ub2, SEL);
    float r0 = a.x - __uint_as_float(ua0 & 0xffff0000u);
    float r1 = a.y - __uint_as_float(ua1 & 0xffff0000u);
    float r2 = a.z - __uint_as_float(ua2 & 0xffff0000u);
    float r3 = a.w - __uint_as_float(ua3 & 0xffff0000u);
    float r4 = b.x - __uint_as_float(ub0 & 0xffff0000u);
    float r5 = b.y - __uint_as_float(ub1 & 0xffff0000u);
    float r6 = b.z - __uint_as_float(ub2 & 0xffff0000u);
    float r7 = b.w - __uint_as_float(ub3 & 0xffff0000u);
    l.u[0] = __builtin_amdgcn_perm(__float_as_uint(r1), __float_as_uint(r0), SEL);
    l.u[1] = __builtin_amdgcn_perm(__float_as_uint(r3), __float_as_uint(r2), SEL);
    l.u[2] = __builtin_amdgcn_perm(__float_as_uint(r5), __float_as_uint(r4), SEL);
    l.u[3] = __builtin_amdgcn_perm(__float_as_uint(r7), __float_as_uint(r6), SEL);
    hi = h.s; lo = l.s;
}

__device__ __forceinline__ float dot8(float4 a, float4 b, float4 c, float4 d, float s) {
    s = fmaf(a.x, c.x, s); s = fmaf(a.y, c.y, s);
    s = fmaf(a.z, c.z, s); s = fmaf(a.w, c.w, s);
    s = fmaf(b.x, d.x, s); s = fmaf(b.y, d.y, s);
    s = fmaf(b.z, d.z, s); s = fmaf(b.w, d.w, s);
    return s;
}

__global__ __launch_bounds__(NTH) void hyper_fused(
    const float* __restrict__ x,
    const float* __restrict__ w,
    const float* __restrict__ bia,
    float* __restrict__ out)
{
    const int wave = threadIdx.x >> 6;
    const int lane = threadIdx.x & 63;
    const int q = lane >> 4, i = lane & 15;
    const int waveid = blockIdx.x * 4 + wave;
    const int m0 = (waveid >> 3) * 16;            // batch-row tile
    const int n0 = (waveid & 7) * 16;             // out-col tile

    const float* xr = x + (size_t)(m0 + i) * NIN + q * 8;   // A: m=i, k=q*8+j
    const float* wr = w + (size_t)(n0 + i) * NIN + q * 8;   // B: n=i, k=q*8+j
    const float* br = bia + (size_t)(n0 + i) * NIN + q * 8;

    floatx4 accW1 = {0.f, 0.f, 0.f, 0.f}, accW2 = {0.f, 0.f, 0.f, 0.f};
    floatx4 accB1 = {0.f, 0.f, 0.f, 0.f}, accB2 = {0.f, 0.f, 0.f, 0.f};
    float vv = 0.f, uu = 0.f, bw = 0.f, ww = 0.f;

    #pragma unroll
    for (int kc = 0; kc < 4; ++kc) {
        const float4 xa = *(const float4*)(xr + kc * 32);
        const float4 xb = *(const float4*)(xr + kc * 32 + 4);
        const float4 wa = *(const float4*)(wr + kc * 32);
        const float4 wb = *(const float4*)(wr + kc * 32 + 4);
        const float4 ba = *(const float4*)(br + kc * 32);
        const float4 bb = *(const float4*)(br + kc * 32 + 4);

        // exact fp32 stats from the same registers
        vv = dot8(xa, xb, xa, xb, vv);
        uu = dot8(ba, bb, ba, bb, uu);
        bw = dot8(ba, bb, wa, wb, bw);
        ww = dot8(wa, wb, wa, wb, ww);

        short8 ah, al, wh, wl, bh, bl;
        cvt_frag(xa, xb, ah, al);
        cvt_frag(wa, wb, wh, wl);
        cvt_frag(ba, bb, bh, bl);

        accW1 = __builtin_amdgcn_mfma_f32_16x16x32_bf16(ah, wh, accW1, 0, 0, 0);
        accB1 = __builtin_amdgcn_mfma_f32_16x16x32_bf16(ah, bh, accB1, 0, 0, 0);
        accW2 = __builtin_amdgcn_mfma_f32_16x16x32_bf16(ah, wl, accW2, 0, 0, 0);
        accB2 = __builtin_amdgcn_mfma_f32_16x16x32_bf16(ah, bl, accB2, 0, 0, 0);
        accW2 = __builtin_amdgcn_mfma_f32_16x16x32_bf16(al, wh, accW2, 0, 0, 0);
        accB2 = __builtin_amdgcn_mfma_f32_16x16x32_bf16(al, bh, accB2, 0, 0, 0);
    }

    // reduce stats across the 4 k-slices of each row/col (lanes i, i+16, i+32, i+48)
    vv += __shfl_xor(vv, 16); vv += __shfl_xor(vv, 32);
    uu += __shfl_xor(uu, 16); uu += __shfl_xor(uu, 32);
    bw += __shfl_xor(bw, 16); bw += __shfl_xor(bw, 32);
    ww += __shfl_xor(ww, 16); ww += __shfl_xor(ww, 32);

    // per-column epilogue constants (col = n0+i, already in this lane)
    const float EPS = 1.1920928955078125e-7f;
    const float CLAMPV = 16.635532333438687f;
    const float INV_SMOOTH = 1.f / 50.f;
    const float SMOOTHF = 50.f;
    const float MAXNORM = 1.f - 1e-5f;

    const float beta = 1.f - uu;
    const float beta_c = fmaxf(beta, EPS);
    const float a_norm = fmaxf(beta_c * sqrtf(ww), 1e-15f);
    const float ba_ = beta_c * bw;
    const float outcoef = (2.f / beta_c) * a_norm;
    const float inv_anorm = 1.f / a_norm;

    #pragma unroll
    for (int r = 0; r < 4; ++r) {
        const int row = m0 + q * 4 + r;                   // C/D: row = quad*4 + reg
        const float vvr = __shfl(vv, q * 4 + r, 64);      // vv[row] from lane (q*4+r)
        const float uv = -(accB1[r] + accB2[r]);
        const float xw = accW1[r] + accW2[r];
        const float dax = beta_c * xw;
        const float alpha = 1.f + 2.f * uv + vvr;
        const float den = fmaxf(1.f + 2.f * uv + uu * vvr, EPS);
        const float inv_den = 1.f / den;
        float suba = (beta * dax - alpha * ba_) * inv_den;
        float ss = (alpha * alpha * uu + 2.f * alpha * beta * uv + beta * beta * vvr)
                   * (inv_den * inv_den);
        const float nrm = fmaxf(sqrtf(fmaxf(ss, 0.f)), 1e-15f);
        if (nrm > MAXNORM) {
            const float sc = MAXNORM / nrm;
            suba *= sc;
            ss *= sc * sc;
        }
        const float lam_sub = 2.f / fmaxf(1.f - ss, EPS);
        const float arg = lam_sub * suba * inv_anorm;
        // smooth clamp with HW transcendentals
        const float t1 = SMOOTHF * (arg + CLAMPV);
        const float t2 = SMOOTHF * (arg - CLAMPV);
        const float sp1 = fmaxf(t1, 0.f) + __logf(1.f + __expf(-fabsf(t1)));
        const float sp2 = fmaxf(t2, 0.f) + __logf(1.f + __expf(-fabsf(t2)));
        const float scl = -CLAMPV + (sp1 - sp2) * INV_SMOOTH;
        // asinh via hw log, sign-split to avoid cancellation
        const float s_ = fabsf(scl);
        const float sd = copysignf(__logf(s_ + sqrtf(fmaf(s_, s_, 1.f))), scl);
        out[(size_t)row * NOUT + n0 + i] = outcoef * sd;
    }
}

extern "C" void kernel_launch(void* const* d_in, const int* in_sizes, int n_in,
                              void* d_out, int out_size, void* d_ws, size_t ws_size,
                              hipStream_t stream) {
    const float* x = (const float*)d_in[0];
    const float* w = (const float*)d_in[1];
    const float* b = (const float*)d_in[2];
    float* out = (float*)d_out;
    const int B = in_sizes[0] / NIN;                       // 4096
    const int nblocks = (B / 16) * (NOUT / 16) / 4;        // 512
    hipLaunchKernelGGL(hyper_fused, dim3(nblocks), dim3(NTH), 0, stream,
                       x, w, b, out);
}

// Round 7
// 64.526 us; speedup vs baseline: 1.6527x; 1.0032x over previous
//
#include <hip/hip_runtime.h>
#include <math.h>

typedef __attribute__((ext_vector_type(8))) short short8;
typedef __attribute__((ext_vector_type(4))) float floatx4;

#define NIN 128
#define NOUT 128
#define NTH 128   // 2 waves/block, 1024 blocks -> finer dispatch than 256x512

union FragU { unsigned u[4]; short8 s; };

// Split 8 fp32 (two float4) into bf16 hi (trunc) + bf16 lo (trunc residual).
__device__ __forceinline__ void cvt_frag(float4 a, float4 b, short8& hi, short8& lo) {
    const unsigned SEL = 0x07060302u;
    unsigned ua0 = __float_as_uint(a.x), ua1 = __float_as_uint(a.y);
    unsigned ua2 = __float_as_uint(a.z), ua3 = __float_as_uint(a.w);
    unsigned ub0 = __float_as_uint(b.x), ub1 = __float_as_uint(b.y);
    unsigned ub2 = __float_as_uint(b.z), ub3 = __float_as_uint(b.w);
    FragU h, l;
    h.u[0] = __builtin_amdgcn_perm(ua1, ua0, SEL);
    h.u[1] = __builtin_amdgcn_perm(ua3, ua2, SEL);
    h.u[2] = __builtin_amdgcn_perm(ub1, ub0, SEL);
    h.u[3] = __builtin_amdgcn_perm(ub3, ub2, SEL);
    float r0 = a.x - __uint_as_float(ua0 & 0xffff0000u);
    float r1 = a.y - __uint_as_float(ua1 & 0xffff0000u);
    float r2 = a.z - __uint_as_float(ua2 & 0xffff0000u);
    float r3 = a.w - __uint_as_float(ua3 & 0xffff0000u);
    float r4 = b.x - __uint_as_float(ub0 & 0xffff0000u);
    float r5 = b.y - __uint_as_float(ub1 & 0xffff0000u);
    float r6 = b.z - __uint_as_float(ub2 & 0xffff0000u);
    float r7 = b.w - __uint_as_float(ub3 & 0xffff0000u);
    l.u[0] = __builtin_amdgcn_perm(__float_as_uint(r1), __float_as_uint(r0), SEL);
    l.u[1] = __builtin_amdgcn_perm(__float_as_uint(r3), __float_as_uint(r2), SEL);
    l.u[2] = __builtin_amdgcn_perm(__float_as_uint(r5), __float_as_uint(r4), SEL);
    l.u[3] = __builtin_amdgcn_perm(__float_as_uint(r7), __float_as_uint(r6), SEL);
    hi = h.s; lo = l.s;
}

__device__ __forceinline__ float dot8(float4 a, float4 b, float4 c, float4 d, float s) {
    s = fmaf(a.x, c.x, s); s = fmaf(a.y, c.y, s);
    s = fmaf(a.z, c.z, s); s = fmaf(a.w, c.w, s);
    s = fmaf(b.x, d.x, s); s = fmaf(b.y, d.y, s);
    s = fmaf(b.z, d.z, s); s = fmaf(b.w, d.w, s);
    return s;
}

__global__ __launch_bounds__(NTH) void hyper_fused(
    const float* __restrict__ x,
    const float* __restrict__ w,
    const float* __restrict__ bia,
    float* __restrict__ out)
{
    const int wave = threadIdx.x >> 6;
    const int lane = threadIdx.x & 63;
    const int q = lane >> 4, i = lane & 15;
    const int waveid = blockIdx.x * 2 + wave;
    const int m0 = (waveid >> 3) * 16;            // batch-row tile
    const int n0 = (waveid & 7) * 16;             // out-col tile

    const float* xr = x + (size_t)(m0 + i) * NIN + q * 8;   // A: m=i, k=q*8+j
    const float* wr = w + (size_t)(n0 + i) * NIN + q * 8;   // B: n=i, k=q*8+j
    const float* br = bia + (size_t)(n0 + i) * NIN + q * 8;

    // issue ALL global loads up front -> deep vmcnt pipeline, one latency wait
    float4 xa[4], xb[4], wa[4], wb[4], ba[4], bb[4];
    #pragma unroll
    for (int kc = 0; kc < 4; ++kc) {
        xa[kc] = *(const float4*)(xr + kc * 32);
        xb[kc] = *(const float4*)(xr + kc * 32 + 4);
        wa[kc] = *(const float4*)(wr + kc * 32);
        wb[kc] = *(const float4*)(wr + kc * 32 + 4);
        ba[kc] = *(const float4*)(br + kc * 32);
        bb[kc] = *(const float4*)(br + kc * 32 + 4);
    }

    floatx4 accW1 = {0.f, 0.f, 0.f, 0.f}, accW2 = {0.f, 0.f, 0.f, 0.f};
    floatx4 accB1 = {0.f, 0.f, 0.f, 0.f}, accB2 = {0.f, 0.f, 0.f, 0.f};
    float vv = 0.f, uu = 0.f, bw = 0.f, ww = 0.f;

    #pragma unroll
    for (int kc = 0; kc < 4; ++kc) {
        vv = dot8(xa[kc], xb[kc], xa[kc], xb[kc], vv);
        uu = dot8(ba[kc], bb[kc], ba[kc], bb[kc], uu);
        bw = dot8(ba[kc], bb[kc], wa[kc], wb[kc], bw);
        ww = dot8(wa[kc], wb[kc], wa[kc], wb[kc], ww);

        short8 ah, al, wh, wl, bh, bl;
        cvt_frag(xa[kc], xb[kc], ah, al);
        cvt_frag(wa[kc], wb[kc], wh, wl);
        cvt_frag(ba[kc], bb[kc], bh, bl);

        accW1 = __builtin_amdgcn_mfma_f32_16x16x32_bf16(ah, wh, accW1, 0, 0, 0);
        accB1 = __builtin_amdgcn_mfma_f32_16x16x32_bf16(ah, bh, accB1, 0, 0, 0);
        accW2 = __builtin_amdgcn_mfma_f32_16x16x32_bf16(ah, wl, accW2, 0, 0, 0);
        accB2 = __builtin_amdgcn_mfma_f32_16x16x32_bf16(ah, bl, accB2, 0, 0, 0);
        accW2 = __builtin_amdgcn_mfma_f32_16x16x32_bf16(al, wh, accW2, 0, 0, 0);
        accB2 = __builtin_amdgcn_mfma_f32_16x16x32_bf16(al, bh, accB2, 0, 0, 0);
    }

    // reduce stats across the 4 k-slices (lanes i, i+16, i+32, i+48)
    vv += __shfl_xor(vv, 16); vv += __shfl_xor(vv, 32);
    uu += __shfl_xor(uu, 16); uu += __shfl_xor(uu, 32);
    bw += __shfl_xor(bw, 16); bw += __shfl_xor(bw, 32);
    ww += __shfl_xor(ww, 16); ww += __shfl_xor(ww, 32);

    // vv[row] for this lane's 4 output rows (hoisted out of epilogue loop)
    float vvr[4];
    #pragma unroll
    for (int r = 0; r < 4; ++r) vvr[r] = __shfl(vv, q * 4 + r, 64);

    const float EPS = 1.1920928955078125e-7f;
    const float CLAMPV = 16.635532333438687f;
    const float INV_SMOOTH = 1.f / 50.f;
    const float SMOOTHF = 50.f;
    const float MAXNORM = 1.f - 1e-5f;

    const float beta = 1.f - uu;
    const float beta_c = fmaxf(beta, EPS);
    const float a_norm = fmaxf(beta_c * sqrtf(ww), 1e-15f);
    const float ba_ = beta_c * bw;
    const float outcoef = (2.f / beta_c) * a_norm;
    const float inv_anorm = 1.f / a_norm;

    #pragma unroll
    for (int r = 0; r < 4; ++r) {
        const int row = m0 + q * 4 + r;                   // C/D: row = quad*4 + reg
        const float vr = vvr[r];
        const float uv = -(accB1[r] + accB2[r]);
        const float xw = accW1[r] + accW2[r];
        const float dax = beta_c * xw;
        const float alpha = 1.f + 2.f * uv + vr;
        const float den = fmaxf(1.f + 2.f * uv + uu * vr, EPS);
        const float inv_den = 1.f / den;
        float suba = (beta * dax - alpha * ba_) * inv_den;
        float ss = (alpha * alpha * uu + 2.f * alpha * beta * uv + beta * beta * vr)
                   * (inv_den * inv_den);
        const float nrm = fmaxf(sqrtf(fmaxf(ss, 0.f)), 1e-15f);
        if (nrm > MAXNORM) {
            const float sc = MAXNORM / nrm;
            suba *= sc;
            ss *= sc * sc;
        }
        const float lam_sub = 2.f / fmaxf(1.f - ss, EPS);
        const float arg = lam_sub * suba * inv_anorm;
        const float t1 = SMOOTHF * (arg + CLAMPV);
        const float t2 = SMOOTHF * (arg - CLAMPV);
        const float sp1 = fmaxf(t1, 0.f) + __logf(1.f + __expf(-fabsf(t1)));
        const float sp2 = fmaxf(t2, 0.f) + __logf(1.f + __expf(-fabsf(t2)));
        const float scl = -CLAMPV + (sp1 - sp2) * INV_SMOOTH;
        const float s_ = fabsf(scl);
        const float sd = copysignf(__logf(s_ + sqrtf(fmaf(s_, s_, 1.f))), scl);
        out[(size_t)row * NOUT + n0 + i] = outcoef * sd;
    }
}

extern "C" void kernel_launch(void* const* d_in, const int* in_sizes, int n_in,
                              void* d_out, int out_size, void* d_ws, size_t ws_size,
                              hipStream_t stream) {
    const float* x = (const float*)d_in[0];
    const float* w = (const float*)d_in[1];
    const float* b = (const float*)d_in[2];
    float* out = (float*)d_out;
    const int B = in_sizes[0] / NIN;                       // 4096
    const int nblocks = (B / 16) * (NOUT / 16) / 2;        // 1024 (2 waves each)
    hipLaunchKernelGGL(hyper_fused, dim3(nblocks), dim3(NTH), 0, stream,
                       x, w, b, out);
}